// Round 10
// baseline (323.687 us; speedup 1.0000x reference)
//
#include <hip/hip_runtime.h>
#include <hip/hip_bf16.h>
#include <math.h>

#define B_  2
#define L_  2048
#define D_  256
#define H_  8
#define HD_ 32
#define F_  1024
#define LY_ 4
#define M_  (B_*L_)

typedef __attribute__((ext_vector_type(8))) short bf16x8;   // 8 bf16 in 4 VGPRs
typedef __attribute__((ext_vector_type(4))) float f32x4;

static __device__ __forceinline__ short f2bf(float f) {
    return __builtin_bit_cast(short, __float2bfloat16(f));
}

static __device__ __forceinline__ void gload_lds16(const ushort* g, ushort* l) {
    __builtin_amdgcn_global_load_lds(
        (const __attribute__((address_space(1))) void*)g,
        (__attribute__((address_space(3))) void*)l, 16, 0, 0);
}

// ---------------------------------------------------------------------------
// Weight transpose + fp32->bf16:  W[K][N] -> Wt[N][K] bf16  (unchanged)
// ---------------------------------------------------------------------------
__global__ __launch_bounds__(256) void transpose_weights(
    const float* __restrict__ Win, const float* __restrict__ Wq,
    const float* __restrict__ Wk,  const float* __restrict__ Wv,
    const float* __restrict__ Wo,  const float* __restrict__ W1,
    const float* __restrict__ W2,  const float* __restrict__ Wout,
    ushort* __restrict__ T)
{
    const int bid = blockIdx.x;
    const float* src; ushort* dst; int K, N, tt;
    if (bid < 64)        { src = Win; dst = T; K = 256; N = 256; tt = bid; }
    else if (bid < 1088) {
        int i = bid - 64; int which = i >> 8; int l = (i >> 6) & 3; tt = i & 63;
        K = 256; N = 256;
        const float* s4[4] = {Wq, Wk, Wv, Wo};
        src = s4[which] + l * 65536;
        dst = T + 65536 * (1 + which * 4 + l);
    } else if (bid < 2112) {
        int i = bid - 1088; int l = i >> 8; tt = i & 255; K = 256; N = 1024;
        src = W1 + l * 262144; dst = T + 65536 * 17 + l * 262144;
    } else if (bid < 3136) {
        int i = bid - 2112; int l = i >> 8; tt = i & 255; K = 1024; N = 256;
        src = W2 + l * 262144; dst = T + 65536 * 17 + 1048576 + l * 262144;
    } else {
        src = Wout; dst = T + 65536 * 17 + 2097152; K = 256; N = 256; tt = bid - 3136;
    }
    const int ntn = N >> 5;
    const int tk = tt / ntn, tn = tt % ntn;
    __shared__ float ld[32][33];
    const int t = threadIdx.x;
    const int r = t >> 3, c4 = (t & 7) * 4;
    float4 v = *reinterpret_cast<const float4*>(&src[(size_t)(tk * 32 + r) * N + tn * 32 + c4]);
    ld[r][c4 + 0] = v.x; ld[r][c4 + 1] = v.y; ld[r][c4 + 2] = v.z; ld[r][c4 + 3] = v.w;
    __syncthreads();
    short4 o;
    o.x = f2bf(ld[c4 + 0][r]);
    o.y = f2bf(ld[c4 + 1][r]);
    o.z = f2bf(ld[c4 + 2][r]);
    o.w = f2bf(ld[c4 + 3][r]);
    *reinterpret_cast<short4*>(&dst[(size_t)(tn * 32 + r) * K + tk * 32 + c4]) = o;
}

// ---------------------------------------------------------------------------
// Self-contained LN-fused consumer core (K=256): coalesced fp32 A-tile load;
// per-row LN stats via in-wave 64-lane butterfly (each wave holds complete
// rows 4j+wid across its lanes) — NO cross-kernel stats; bf16 A-tile in LDS
// [64][264]; W streamed via async global_load_lds, double-buffered.
// LNM: 0 = convert-only, 1 = LayerNorm.
// ---------------------------------------------------------------------------
template<int LNM>
__device__ __forceinline__ void core_f(
    const float* __restrict__ Hin, const float* __restrict__ lng,
    const float* __restrict__ lnb, const ushort* __restrict__ Wt,
    int row0, int col0, ushort* sLN, ushort* sW, f32x4 acc[2][2])
{
    const int tid  = threadIdx.x;
    const int lane = tid & 63;
    const int wid  = tid >> 6;
    const int wr = wid >> 1, wc = wid & 1;
    const int g = lane >> 4, nn = lane & 15;

    // W DMA for k0=0 (in flight across the prologue)
    const int r0 = tid >> 3;
    const int sx = ((tid & 7) ^ (r0 & 7)) << 3;
    const ushort* Wp = &Wt[(size_t)(col0 + r0) * 256 + sx];
    ushort* ldsW = sW + wid * 512;
    gload_lds16(Wp,            ldsW);
    gload_lds16(Wp + 32 * 256, ldsW + 2048);

    // A-tile: fully coalesced fp32 loads; lane holds float4-col `lane` of
    // rows {4j + wid}.
    const float4* hp = reinterpret_cast<const float4*>(Hin + (size_t)row0 * D_);
    float4 av[16];
#pragma unroll
    for (int j = 0; j < 16; ++j) av[j] = hp[j * 256 + tid];

    float4 g4, b4;
    if (LNM) {
        g4 = reinterpret_cast<const float4*>(lng)[lane];
        b4 = reinterpret_cast<const float4*>(lnb)[lane];
    }
#pragma unroll
    for (int j = 0; j < 16; ++j) {
        const float4 v = av[j];
        short4 o;
        if (LNM) {
            float s  = v.x + v.y + v.z + v.w;
            float s2 = v.x * v.x + v.y * v.y + v.z * v.z + v.w * v.w;
            s  += __shfl_xor(s, 1);  s  += __shfl_xor(s, 2);  s  += __shfl_xor(s, 4);
            s  += __shfl_xor(s, 8);  s  += __shfl_xor(s, 16); s  += __shfl_xor(s, 32);
            s2 += __shfl_xor(s2, 1); s2 += __shfl_xor(s2, 2); s2 += __shfl_xor(s2, 4);
            s2 += __shfl_xor(s2, 8); s2 += __shfl_xor(s2, 16); s2 += __shfl_xor(s2, 32);
            const float mean = s * (1.0f / D_);
            const float var  = s2 * (1.0f / D_) - mean * mean;
            const float rstd = rsqrtf(var + 1e-5f);
            o.x = f2bf((v.x - mean) * rstd * g4.x + b4.x);
            o.y = f2bf((v.y - mean) * rstd * g4.y + b4.y);
            o.z = f2bf((v.z - mean) * rstd * g4.z + b4.z);
            o.w = f2bf((v.w - mean) * rstd * g4.w + b4.w);
        } else {
            o.x = f2bf(v.x); o.y = f2bf(v.y); o.z = f2bf(v.z); o.w = f2bf(v.w);
        }
        *reinterpret_cast<short4*>(&sLN[(j * 4 + wid) * 264 + lane * 4]) = o;
    }
    __syncthreads();   // sLN visible; W buf0 landed (barrier drains vmcnt)

    const int ra = (wr * 32 + nn) * 264, rb = ra + 16 * 264;
    const int rc = (wc * 32 + nn) * 64,  rd = rc + 16 * 64;
    const int m7 = nn & 7;

    int cur = 0;
#pragma unroll
    for (int k0 = 0; k0 < 256; k0 += 64) {
        if (k0 + 64 < 256) {
            ushort* lW = ldsW + (cur ^ 1) * 4096;
            gload_lds16(Wp + k0 + 64,            lW);
            gload_lds16(Wp + k0 + 64 + 32 * 256, lW + 2048);
        }
        const ushort* w = sW + cur * 4096;
#pragma unroll
        for (int sk = 0; sk < 2; ++sk) {
            const int ac = k0 + sk * 32 + g * 8;
            bf16x8 a0 = *reinterpret_cast<const bf16x8*>(&sLN[ra + ac]);
            bf16x8 a1 = *reinterpret_cast<const bf16x8*>(&sLN[rb + ac]);
            const int sw = ((sk * 4 + g) ^ m7) << 3;
            bf16x8 w0 = *reinterpret_cast<const bf16x8*>(&w[rc + sw]);
            bf16x8 w1 = *reinterpret_cast<const bf16x8*>(&w[rd + sw]);
            acc[0][0] = __builtin_amdgcn_mfma_f32_16x16x32_bf16(a0, w0, acc[0][0], 0, 0, 0);
            acc[0][1] = __builtin_amdgcn_mfma_f32_16x16x32_bf16(a0, w1, acc[0][1], 0, 0, 0);
            acc[1][0] = __builtin_amdgcn_mfma_f32_16x16x32_bf16(a1, w0, acc[1][0], 0, 0, 0);
            acc[1][1] = __builtin_amdgcn_mfma_f32_16x16x32_bf16(a1, w1, acc[1][1], 0, 0, 0);
        }
        __syncthreads();
        cur ^= 1;
    }
}

// ---------------------------------------------------------------------------
// LN-fused GEMM + epilogue. LNM 0/1; EPI: 0 none, 1 exact GELU; OUTBF.
// ---------------------------------------------------------------------------
template<int LNM, int EPI, int OUTBF>
__global__ __launch_bounds__(256) void gemm_fused(
    const float* __restrict__ Hin, const float* __restrict__ lng,
    const float* __restrict__ lnb, const ushort* __restrict__ Wt,
    const float* __restrict__ bias, void* __restrict__ Cout, int N)
{
    __shared__ __align__(16) ushort sLN[64 * 264];
    __shared__ __align__(16) ushort sW[2 * 4096];
    const int row0 = blockIdx.y * 64, col0 = blockIdx.x * 64;
    f32x4 acc[2][2] = {};
    core_f<LNM>(Hin, lng, lnb, Wt, row0, col0, sLN, sW, acc);

    const int lane = threadIdx.x & 63;
    const int wid  = threadIdx.x >> 6;
    const int wr = wid >> 1, wc = wid & 1;
    const int g = lane >> 4, nn = lane & 15;
#pragma unroll
    for (int mi = 0; mi < 2; ++mi)
#pragma unroll
    for (int ni = 0; ni < 2; ++ni)
#pragma unroll
    for (int r = 0; r < 4; ++r) {
        const int m = row0 + wr * 32 + mi * 16 + g * 4 + r;
        const int c = col0 + wc * 32 + ni * 16 + nn;
        float v = acc[mi][ni][r] + bias[c];
        if (EPI == 1) v = 0.5f * v * (1.0f + erff(v * 0.70710678118654752f));
        if (OUTBF) ((ushort*)Cout)[(size_t)m * N + c] = (ushort)f2bf(v);
        else       ((float*)Cout)[(size_t)m * N + c] = v;
    }
}

// ---------------------------------------------------------------------------
// LN-fused QKV GEMM: grid.x = 12 (0-3 Q, 4-7 K, 8-11 V), grid.y = 64.
// Q,K -> bf16 row-major. V -> transposed Vt[b][h][d][l].
// ---------------------------------------------------------------------------
__global__ __launch_bounds__(256) void gemm_qkv_f(
    const float* __restrict__ Hin, const float* __restrict__ lng,
    const float* __restrict__ lnb,
    const ushort* __restrict__ WqT, const ushort* __restrict__ WkT,
    const ushort* __restrict__ WvT,
    const float* __restrict__ bq, const float* __restrict__ bk,
    const float* __restrict__ bv,
    ushort* __restrict__ Qb, ushort* __restrict__ Kb, ushort* __restrict__ Vt)
{
    __shared__ __align__(16) ushort sLN[64 * 264];
    __shared__ __align__(16) ushort sW[2 * 4096];
    const int nb = blockIdx.x;
    const int wsel = nb >> 2;
    const int col0 = (nb & 3) * 64;
    const int row0 = blockIdx.y * 64;
    const ushort* Wt = (wsel == 0) ? WqT : (wsel == 1) ? WkT : WvT;
    const float* bias = (wsel == 0) ? bq : (wsel == 1) ? bk : bv;

    f32x4 acc[2][2] = {};
    core_f<1>(Hin, lng, lnb, Wt, row0, col0, sLN, sW, acc);

    const int lane = threadIdx.x & 63;
    const int wid  = threadIdx.x >> 6;
    const int wr = wid >> 1, wc = wid & 1;
    const int g = lane >> 4, nn = lane & 15;
    ushort* QK = (wsel == 0) ? Qb : Kb;
#pragma unroll
    for (int mi = 0; mi < 2; ++mi)
#pragma unroll
    for (int ni = 0; ni < 2; ++ni)
#pragma unroll
    for (int r = 0; r < 4; ++r) {
        const int m = row0 + wr * 32 + mi * 16 + g * 4 + r;
        const int c = col0 + wc * 32 + ni * 16 + nn;
        const float v = acc[mi][ni][r] + bias[c];
        if (wsel < 2) {
            QK[(size_t)m * D_ + c] = (ushort)f2bf(v);
        } else {
            const int b = m >> 11, l = m & 2047;
            const int h = c >> 5,  d = c & 31;
            Vt[(size_t)((b * 8 + h) * 32 + d) * L_ + l] = (ushort)f2bf(v);
        }
    }
}

// ---------------------------------------------------------------------------
// bf16-A GEMM (round-6 verified core) + residual epilogue. Wo / FF2.
// ---------------------------------------------------------------------------
__device__ __forceinline__ void gemm_core64(
    const ushort* __restrict__ A, const ushort* __restrict__ Wt, int K,
    int row0, int col0, ushort* sA, ushort* sW, f32x4 acc[2][2])
{
    const int tid  = threadIdx.x;
    const int lane = tid & 63;
    const int wid  = tid >> 6;
    const int wr = wid >> 1, wc = wid & 1;
    const int g = lane >> 4, nn = lane & 15;

    const int r0 = tid >> 3;
    const int sx = ((tid & 7) ^ (r0 & 7)) << 3;

    const ushort* Ap = &A[(size_t)(row0 + r0) * K + sx];
    const ushort* Wp = &Wt[(size_t)(col0 + r0) * K + sx];
    const size_t rstep = (size_t)32 * K;

    ushort* ldsA = sA + wid * 512;
    ushort* ldsW = sW + wid * 512;

    gload_lds16(Ap,         ldsA);
    gload_lds16(Ap + rstep, ldsA + 2048);
    gload_lds16(Wp,         ldsW);
    gload_lds16(Wp + rstep, ldsW + 2048);

    const int ra = (wr * 32 + nn) * 64, rb = ra + 16 * 64;
    const int rc = (wc * 32 + nn) * 64, rd = rc + 16 * 64;
    const int m7 = nn & 7;

    int cur = 0;
    __syncthreads();
    for (int k0 = 0; k0 < K; k0 += 64) {
        if (k0 + 64 < K) {
            ushort* lA = ldsA + (cur ^ 1) * 4096;
            ushort* lW = ldsW + (cur ^ 1) * 4096;
            gload_lds16(Ap + k0 + 64,         lA);
            gload_lds16(Ap + k0 + 64 + rstep, lA + 2048);
            gload_lds16(Wp + k0 + 64,         lW);
            gload_lds16(Wp + k0 + 64 + rstep, lW + 2048);
        }
        const ushort* a = sA + cur * 4096;
        const ushort* w = sW + cur * 4096;
#pragma unroll
        for (int sk = 0; sk < 2; ++sk) {
            const int sw = ((sk * 4 + g) ^ m7) << 3;
            bf16x8 a0 = *reinterpret_cast<const bf16x8*>(&a[ra + sw]);
            bf16x8 a1 = *reinterpret_cast<const bf16x8*>(&a[rb + sw]);
            bf16x8 w0 = *reinterpret_cast<const bf16x8*>(&w[rc + sw]);
            bf16x8 w1 = *reinterpret_cast<const bf16x8*>(&w[rd + sw]);
            acc[0][0] = __builtin_amdgcn_mfma_f32_16x16x32_bf16(a0, w0, acc[0][0], 0, 0, 0);
            acc[0][1] = __builtin_amdgcn_mfma_f32_16x16x32_bf16(a0, w1, acc[0][1], 0, 0, 0);
            acc[1][0] = __builtin_amdgcn_mfma_f32_16x16x32_bf16(a1, w0, acc[1][0], 0, 0, 0);
            acc[1][1] = __builtin_amdgcn_mfma_f32_16x16x32_bf16(a1, w1, acc[1][1], 0, 0, 0);
        }
        __syncthreads();
        cur ^= 1;
    }
}

__global__ __launch_bounds__(256) void gemm_res(
    const ushort* __restrict__ A, const ushort* __restrict__ Wt,
    const float* __restrict__ bias, float* __restrict__ C, int K)
{
    __shared__ __align__(16) ushort sA[2 * 4096];
    __shared__ __align__(16) ushort sW[2 * 4096];
    const int row0 = blockIdx.y * 64, col0 = blockIdx.x * 64;
    f32x4 acc[2][2] = {};
    gemm_core64(A, Wt, K, row0, col0, sA, sW, acc);

    const int lane = threadIdx.x & 63;
    const int wid  = threadIdx.x >> 6;
    const int wr = wid >> 1, wc = wid & 1;
    const int g = lane >> 4, nn = lane & 15;
#pragma unroll
    for (int mi = 0; mi < 2; ++mi)
#pragma unroll
    for (int ni = 0; ni < 2; ++ni)
#pragma unroll
    for (int r = 0; r < 4; ++r) {
        const int m = row0 + wr * 32 + mi * 16 + g * 4 + r;
        const int c = col0 + wc * 32 + ni * 16 + nn;
        C[(size_t)m * D_ + c] += acc[mi][ni][r] + bias[c];
    }
}

// ---------------------------------------------------------------------------
// MFMA evidence attention (round-7 verified) + fused uncertainty finalize.
// ---------------------------------------------------------------------------
__global__ __launch_bounds__(256) void attn_mfma(
    const ushort* __restrict__ Qb, const ushort* __restrict__ Kb,
    const ushort* __restrict__ Vt, ushort* __restrict__ O,
    float* __restrict__ unc, const float* __restrict__ ev_scale,
    const float* __restrict__ ev_bias, int layer,
    float* __restrict__ out_unc, float* __restrict__ out_abst)
{
    const int bh = blockIdx.y;
    const int b  = bh >> 3;
    const int h  = bh & 7;
    const int tid  = threadIdx.x;
    const int wv   = tid >> 6;
    const int lane = tid & 63;
    const int g = lane >> 4;
    const int n = lane & 15;
    const int q  = blockIdx.x * 64 + wv * 16 + n;
    const float scale = ev_scale[layer];
    const float cb    = 1.0f + ev_bias[layer];
    const float isq   = 0.17677669529663687f;   // 1/sqrt(32)

    __shared__ __align__(16) ushort sK[2][64][40];
    __shared__ __align__(16) ushort sV[2][32][72];

    const size_t qk0 = (size_t)b * L_ * D_ + h * HD_;

    bf16x8 qf;
    {
        const bf16x8 qr = *reinterpret_cast<const bf16x8*>(&Qb[qk0 + (size_t)q * D_ + g * 8]);
#pragma unroll
        for (int j = 0; j < 8; ++j) {
            const float qv = __builtin_bit_cast(float, ((unsigned)(unsigned short)qr[j]) << 16);
            qf[j] = f2bf(qv * isq);
        }
    }
    bf16x8 ones;
#pragma unroll
    for (int j = 0; j < 8; ++j) ones[j] = (short)0x3F80;

    const int krow = tid >> 2, kch = (tid & 3) * 8;
    const int vrow = tid >> 3, vch = (tid & 7) * 8;
    const ushort* ksrc = Kb + qk0 + (size_t)krow * D_ + kch;
    const ushort* vsrc = Vt + (size_t)((b * 8 + h) * 32 + vrow) * L_ + vch;

    f32x4 acc0 = {0.f, 0.f, 0.f, 0.f};
    f32x4 acc1 = {0.f, 0.f, 0.f, 0.f};
    f32x4 accS = {0.f, 0.f, 0.f, 0.f};
    const f32x4 zero = {0.f, 0.f, 0.f, 0.f};

    bf16x8 kreg = *reinterpret_cast<const bf16x8*>(ksrc);
    bf16x8 vreg = *reinterpret_cast<const bf16x8*>(vsrc);

    int cur = 0;
    for (int t = 0; t < L_; t += 64) {
        *reinterpret_cast<bf16x8*>(&sK[cur][krow][kch]) = kreg;
        *reinterpret_cast<bf16x8*>(&sV[cur][vrow][vch]) = vreg;
        if (t + 64 < L_) {
            kreg = *reinterpret_cast<const bf16x8*>(ksrc + (size_t)(t + 64) * D_);
            vreg = *reinterpret_cast<const bf16x8*>(vsrc + (t + 64));
        }
        __syncthreads();

#pragma unroll
        for (int tt = 0; tt < 64; tt += 32) {
            bf16x8 kf0 = *reinterpret_cast<const bf16x8*>(&sK[cur][tt + n][g * 8]);
            bf16x8 kf1 = *reinterpret_cast<const bf16x8*>(&sK[cur][tt + 16 + n][g * 8]);

            f32x4 s0 = __builtin_amdgcn_mfma_f32_16x16x32_bf16(kf0, qf, zero, 0, 0, 0);
            f32x4 s1 = __builtin_amdgcn_mfma_f32_16x16x32_bf16(kf1, qf, zero, 0, 0, 0);

            short4 va = *reinterpret_cast<const short4*>(&sV[cur][n][tt + g * 4]);
            short4 vb = *reinterpret_cast<const short4*>(&sV[cur][n][tt + 16 + g * 4]);
            short4 vc = *reinterpret_cast<const short4*>(&sV[cur][n + 16][tt + g * 4]);
            short4 vd = *reinterpret_cast<const short4*>(&sV[cur][n + 16][tt + 16 + g * 4]);
            bf16x8 vf0 = {va.x, va.y, va.z, va.w, vb.x, vb.y, vb.z, vb.w};
            bf16x8 vf1 = {vc.x, vc.y, vc.z, vc.w, vd.x, vd.y, vd.z, vd.w};

            bf16x8 pa;
#pragma unroll
            for (int r = 0; r < 4; ++r) pa[r]     = f2bf(fmaf(__expf(s0[r]), scale, cb));
#pragma unroll
            for (int r = 0; r < 4; ++r) pa[r + 4] = f2bf(fmaf(__expf(s1[r]), scale, cb));

            acc0 = __builtin_amdgcn_mfma_f32_16x16x32_bf16(vf0, pa, acc0, 0, 0, 0);
            acc1 = __builtin_amdgcn_mfma_f32_16x16x32_bf16(vf1, pa, acc1, 0, 0, 0);
            accS = __builtin_amdgcn_mfma_f32_16x16x32_bf16(ones, pa, accS, 0, 0, 0);
        }
        cur ^= 1;
    }

    const float inv = 1.0f / accS[0];

    ushort* op = &O[qk0 + (size_t)q * D_ + g * 4];
    short4 o0 = {f2bf(acc0[0] * inv), f2bf(acc0[1] * inv), f2bf(acc0[2] * inv), f2bf(acc0[3] * inv)};
    short4 o1 = {f2bf(acc1[0] * inv), f2bf(acc1[1] * inv), f2bf(acc1[2] * inv), f2bf(acc1[3] * inv)};
    *reinterpret_cast<short4*>(op)      = o0;
    *reinterpret_cast<short4*>(op + 16) = o1;

    if (g == 0) {
        const float u = (float)L_ * inv;
        const int uidx = bh * L_ + q;
        if (layer == 0) {
            unc[uidx] = u;                      // '=' : deterministic across replays
        } else if (layer < LY_ - 1) {
            unc[uidx] += u;
        } else {
            const float avg = (unc[uidx] + u) * 0.25f;
            out_unc[uidx]  = avg;
            out_abst[uidx] = (avg > 0.3f) ? 1.0f : 0.0f;
        }
    }
}

// ---------------------------------------------------------------------------
extern "C" void kernel_launch(void* const* d_in, const int* in_sizes, int n_in,
                              void* d_out, int out_size, void* d_ws, size_t ws_size,
                              hipStream_t stream)
{
    const float* x    = (const float*)d_in[0];
    const float* Win  = (const float*)d_in[1];
    const float* bin_ = (const float*)d_in[2];
    const float* Wq   = (const float*)d_in[3];
    const float* bq   = (const float*)d_in[4];
    const float* Wk   = (const float*)d_in[5];
    const float* bk   = (const float*)d_in[6];
    const float* Wv   = (const float*)d_in[7];
    const float* bv   = (const float*)d_in[8];
    const float* Wo   = (const float*)d_in[9];
    const float* bo   = (const float*)d_in[10];
    const float* evs  = (const float*)d_in[11];
    const float* evb  = (const float*)d_in[12];
    const float* W1   = (const float*)d_in[13];
    const float* b1   = (const float*)d_in[14];
    const float* W2   = (const float*)d_in[15];
    const float* b2   = (const float*)d_in[16];
    const float* n1g  = (const float*)d_in[17];
    const float* n1b  = (const float*)d_in[18];
    const float* n2g  = (const float*)d_in[19];
    const float* n2b  = (const float*)d_in[20];
    const float* fng  = (const float*)d_in[21];
    const float* fnb  = (const float*)d_in[22];
    const float* Wout = (const float*)d_in[23];
    const float* bout = (const float*)d_in[24];

    char* ws = (char*)d_ws;
    float*  h    = (float*) (ws);                  // 4 MB fp32 residual stream
    ushort* Qb   = (ushort*)(ws + (6  << 20));     // 2 MB
    ushort* Kb   = (ushort*)(ws + (8  << 20));     // 2 MB
    ushort* Vt   = (ushort*)(ws + (10 << 20));     // 2 MB (transposed V)
    ushort* Ob   = (ushort*)(ws + (12 << 20));     // 2 MB (attn out)
    ushort* ffb  = (ushort*)(ws + (4  << 20));     // 8 MB, overlays Qb..Vt (dead by FF1)
    float*  unc  = (float*) (ws + (14 << 20));     // 128 KB
    ushort* T    = (ushort*)(ws + (15 << 20));     // 6.55 MB bf16 weights

    ushort* winT  = T;
    ushort* woutT = T + 65536 * 17 + 2097152;

    float* out_main = (float*)d_out;
    float* out_unc  = out_main + M_ * D_;
    float* out_abst = out_unc + B_ * H_ * L_;

    const dim3 blk(256);
    const dim3 g256(4, 64);     // N=256 GEMMs
    const dim3 g1024(16, 64);   // N=1024 GEMM
    const dim3 gqkv(12, 64);
    const dim3 gattn(L_ / 64, B_ * H_);

    transpose_weights<<<3200, blk, 0, stream>>>(Win, Wq, Wk, Wv, Wo, W1, W2, Wout, T);
    // h = x @ Win + bin  (convert-only A-prologue; replaces f32_to_bf16 + gemm)
    gemm_fused<0, 0, 0><<<g256, blk, 0, stream>>>(x, nullptr, nullptr, winT, bin_, h, D_);

    for (int i = 0; i < LY_; ++i) {
        ushort* wqT = T + 65536 * (1 + i);
        ushort* wkT = T + 65536 * (5 + i);
        ushort* wvT = T + 65536 * (9 + i);
        ushort* woT = T + 65536 * (13 + i);
        ushort* w1T = T + 65536 * 17 + i * 262144;
        ushort* w2T = T + 65536 * 17 + 1048576 + i * 262144;

        gemm_qkv_f<<<gqkv, blk, 0, stream>>>(h, n1g + i * D_, n1b + i * D_,
                                             wqT, wkT, wvT,
                                             bq + i * D_, bk + i * D_, bv + i * D_,
                                             Qb, Kb, Vt);
        attn_mfma<<<gattn, blk, 0, stream>>>(Qb, Kb, Vt, Ob, unc, evs, evb, i,
                                             out_unc, out_abst);
        gemm_res<<<g256, blk, 0, stream>>>(Ob, woT, bo + i * D_, h, D_);
        gemm_fused<1, 1, 1><<<g1024, blk, 0, stream>>>(h, n2g + i * D_, n2b + i * D_,
                                                       w1T, b1 + i * F_, ffb, F_);
        gemm_res<<<g256, blk, 0, stream>>>(ffb, w2T, b2 + i * D_, h, F_);
    }

    gemm_fused<1, 0, 0><<<g256, blk, 0, stream>>>(h, fng, fnb, woutT, bout, out_main, D_);
}

// Round 11
// 316.091 us; speedup vs baseline: 1.0240x; 1.0240x over previous
//
#include <hip/hip_runtime.h>
#include <hip/hip_bf16.h>
#include <math.h>

#define B_  2
#define L_  2048
#define D_  256
#define H_  8
#define HD_ 32
#define F_  1024
#define LY_ 4
#define M_  (B_*L_)

typedef __attribute__((ext_vector_type(8))) short bf16x8;   // 8 bf16 in 4 VGPRs
typedef __attribute__((ext_vector_type(4))) float f32x4;

static __device__ __forceinline__ short f2bf(float f) {
    return __builtin_bit_cast(short, __float2bfloat16(f));
}

static __device__ __forceinline__ void gload_lds16(const ushort* g, ushort* l) {
    __builtin_amdgcn_global_load_lds(
        (const __attribute__((address_space(1))) void*)g,
        (__attribute__((address_space(3))) void*)l, 16, 0, 0);
}

// ---------------------------------------------------------------------------
// Weight transpose + fp32->bf16:  W[K][N] -> Wt[N][K] bf16  (unchanged)
// ---------------------------------------------------------------------------
__global__ __launch_bounds__(256) void transpose_weights(
    const float* __restrict__ Win, const float* __restrict__ Wq,
    const float* __restrict__ Wk,  const float* __restrict__ Wv,
    const float* __restrict__ Wo,  const float* __restrict__ W1,
    const float* __restrict__ W2,  const float* __restrict__ Wout,
    ushort* __restrict__ T)
{
    const int bid = blockIdx.x;
    const float* src; ushort* dst; int K, N, tt;
    if (bid < 64)        { src = Win; dst = T; K = 256; N = 256; tt = bid; }
    else if (bid < 1088) {
        int i = bid - 64; int which = i >> 8; int l = (i >> 6) & 3; tt = i & 63;
        K = 256; N = 256;
        const float* s4[4] = {Wq, Wk, Wv, Wo};
        src = s4[which] + l * 65536;
        dst = T + 65536 * (1 + which * 4 + l);
    } else if (bid < 2112) {
        int i = bid - 1088; int l = i >> 8; tt = i & 255; K = 256; N = 1024;
        src = W1 + l * 262144; dst = T + 65536 * 17 + l * 262144;
    } else if (bid < 3136) {
        int i = bid - 2112; int l = i >> 8; tt = i & 255; K = 1024; N = 256;
        src = W2 + l * 262144; dst = T + 65536 * 17 + 1048576 + l * 262144;
    } else {
        src = Wout; dst = T + 65536 * 17 + 2097152; K = 256; N = 256; tt = bid - 3136;
    }
    const int ntn = N >> 5;
    const int tk = tt / ntn, tn = tt % ntn;
    __shared__ float ld[32][33];
    const int t = threadIdx.x;
    const int r = t >> 3, c4 = (t & 7) * 4;
    float4 v = *reinterpret_cast<const float4*>(&src[(size_t)(tk * 32 + r) * N + tn * 32 + c4]);
    ld[r][c4 + 0] = v.x; ld[r][c4 + 1] = v.y; ld[r][c4 + 2] = v.z; ld[r][c4 + 3] = v.w;
    __syncthreads();
    short4 o;
    o.x = f2bf(ld[c4 + 0][r]);
    o.y = f2bf(ld[c4 + 1][r]);
    o.z = f2bf(ld[c4 + 2][r]);
    o.w = f2bf(ld[c4 + 3][r]);
    *reinterpret_cast<short4*>(&dst[(size_t)(tn * 32 + r) * K + tk * 32 + c4]) = o;
}

// ---------------------------------------------------------------------------
// First GEMM (x fp32 -> h fp32), round-10 verified: convert-only A prologue,
// async-DMA W stream.
// ---------------------------------------------------------------------------
__global__ __launch_bounds__(256) void gemm_first(
    const float* __restrict__ Hin, const ushort* __restrict__ Wt,
    const float* __restrict__ bias, float* __restrict__ Cout)
{
    __shared__ __align__(16) ushort sLN[64 * 264];
    __shared__ __align__(16) ushort sW[2 * 4096];
    const int row0 = blockIdx.y * 64, col0 = blockIdx.x * 64;
    const int tid  = threadIdx.x;
    const int lane = tid & 63;
    const int wid  = tid >> 6;
    const int wr = wid >> 1, wc = wid & 1;
    const int g = lane >> 4, nn = lane & 15;

    const int r0 = tid >> 3;
    const int sx = ((tid & 7) ^ (r0 & 7)) << 3;
    const ushort* Wp = &Wt[(size_t)(col0 + r0) * 256 + sx];
    ushort* ldsW = sW + wid * 512;
    gload_lds16(Wp,            ldsW);
    gload_lds16(Wp + 32 * 256, ldsW + 2048);

    const float4* hp = reinterpret_cast<const float4*>(Hin + (size_t)row0 * D_);
#pragma unroll
    for (int j = 0; j < 16; ++j) {
        const float4 v = hp[j * 256 + tid];
        short4 o = {f2bf(v.x), f2bf(v.y), f2bf(v.z), f2bf(v.w)};
        *reinterpret_cast<short4*>(&sLN[(j * 4 + wid) * 264 + lane * 4]) = o;
    }
    __syncthreads();

    const int ra = (wr * 32 + nn) * 264, rb = ra + 16 * 264;
    const int rc = (wc * 32 + nn) * 64,  rd = rc + 16 * 64;
    const int m7 = nn & 7;
    f32x4 acc[2][2] = {};

    int cur = 0;
#pragma unroll
    for (int k0 = 0; k0 < 256; k0 += 64) {
        if (k0 + 64 < 256) {
            ushort* lW = ldsW + (cur ^ 1) * 4096;
            gload_lds16(Wp + k0 + 64,            lW);
            gload_lds16(Wp + k0 + 64 + 32 * 256, lW + 2048);
        }
        const ushort* w = sW + cur * 4096;
#pragma unroll
        for (int sk = 0; sk < 2; ++sk) {
            const int ac = k0 + sk * 32 + g * 8;
            bf16x8 a0 = *reinterpret_cast<const bf16x8*>(&sLN[ra + ac]);
            bf16x8 a1 = *reinterpret_cast<const bf16x8*>(&sLN[rb + ac]);
            const int sw = ((sk * 4 + g) ^ m7) << 3;
            bf16x8 w0 = *reinterpret_cast<const bf16x8*>(&w[rc + sw]);
            bf16x8 w1 = *reinterpret_cast<const bf16x8*>(&w[rd + sw]);
            acc[0][0] = __builtin_amdgcn_mfma_f32_16x16x32_bf16(a0, w0, acc[0][0], 0, 0, 0);
            acc[0][1] = __builtin_amdgcn_mfma_f32_16x16x32_bf16(a0, w1, acc[0][1], 0, 0, 0);
            acc[1][0] = __builtin_amdgcn_mfma_f32_16x16x32_bf16(a1, w0, acc[1][0], 0, 0, 0);
            acc[1][1] = __builtin_amdgcn_mfma_f32_16x16x32_bf16(a1, w1, acc[1][1], 0, 0, 0);
        }
        __syncthreads();
        cur ^= 1;
    }

#pragma unroll
    for (int mi = 0; mi < 2; ++mi)
#pragma unroll
    for (int ni = 0; ni < 2; ++ni)
#pragma unroll
    for (int r = 0; r < 4; ++r) {
        const int m = row0 + wr * 32 + mi * 16 + g * 4 + r;
        const int c = col0 + wc * 32 + ni * 16 + nn;
        Cout[(size_t)m * D_ + c] = acc[mi][ni][r] + bias[c];
    }
}

// ---------------------------------------------------------------------------
// Mega-kernel helpers: 16-row GEMM with W streamed in 256x64 chunks.
// ---------------------------------------------------------------------------
static __device__ __forceinline__ void stageW(
    const ushort* __restrict__ W, int K, int k0, ushort* dst, int wid, int lane)
{
    const int rsub = lane >> 3;
    const int slot = ((lane & 7) ^ (rsub & 7)) << 3;
#pragma unroll
    for (int q = 0; q < 8; ++q) {
        const int r = (wid * 8 + q) * 8 + rsub;
        gload_lds16(W + (size_t)r * K + k0 + slot, dst + (wid * 8 + q) * 512);
    }
}

// One n-chunk (256 cols, wave wid owns cols wid*64..+64) x K. A in LDS
// (rows 0..15, stride As ushorts). Leading/trailing __syncthreads included.
template<typename EPI>
static __device__ __forceinline__ void gemm_nchunk(
    const ushort* __restrict__ Wt, int K, const ushort* sA, int As,
    ushort* sW, int wid, int lane, EPI epi)
{
    const int g = lane >> 4, nn = lane & 15;
    stageW(Wt, K, 0, sW, wid, lane);
    int cur = 0;
    f32x4 acc[4] = {};
    const int nkc = K >> 6;
    for (int kc = 0; kc < nkc; ++kc) {
        __syncthreads();                        // chunk kc landed; prev buf free
        if (kc + 1 < nkc) stageW(Wt, K, (kc + 1) * 64, sW + (cur ^ 1) * 16384, wid, lane);
        const ushort* w = sW + cur * 16384;
#pragma unroll
        for (int sk = 0; sk < 2; ++sk) {
            bf16x8 a = *reinterpret_cast<const bf16x8*>(&sA[nn * As + kc * 64 + sk * 32 + g * 8]);
            const int ws = ((sk * 4 + g) ^ (nn & 7)) << 3;
#pragma unroll
            for (int ni = 0; ni < 4; ++ni) {
                const int wrow = wid * 64 + ni * 16 + nn;
                bf16x8 wf = *reinterpret_cast<const bf16x8*>(&w[wrow * 64 + ws]);
                acc[ni] = __builtin_amdgcn_mfma_f32_16x16x32_bf16(a, wf, acc[ni], 0, 0, 0);
            }
        }
        cur ^= 1;
    }
    __syncthreads();                            // all MFMAs done; sW reusable
    epi(acc);
}

// In-block LayerNorm over 16 rows x 256 cols: sH fp32 -> sA bf16 [16][264].
static __device__ __forceinline__ void ln16(
    const float* sH, ushort* sA, const float* __restrict__ gg,
    const float* __restrict__ bb, int tid)
{
    const int row = tid >> 4, sc = (tid & 15) * 16;
    float v[16];
#pragma unroll
    for (int j = 0; j < 16; ++j) v[j] = sH[row * 256 + sc + j];
    float s = 0.f, s2 = 0.f;
#pragma unroll
    for (int j = 0; j < 16; ++j) { s += v[j]; s2 += v[j] * v[j]; }
    s  += __shfl_xor(s, 1);  s  += __shfl_xor(s, 2);
    s  += __shfl_xor(s, 4);  s  += __shfl_xor(s, 8);
    s2 += __shfl_xor(s2, 1); s2 += __shfl_xor(s2, 2);
    s2 += __shfl_xor(s2, 4); s2 += __shfl_xor(s2, 8);
    const float mean = s * (1.0f / D_);
    const float var  = s2 * (1.0f / D_) - mean * mean;
    const float rstd = rsqrtf(var + 1e-5f);
#pragma unroll
    for (int j = 0; j < 16; ++j)
        sA[row * 264 + sc + j] = (ushort)f2bf((v[j] - mean) * rstd * gg[sc + j] + bb[sc + j]);
}

// ---------------------------------------------------------------------------
// Mega kernel: per block = 16 complete rows. DO_FFN: attnOut@Wo+res -> LN2 ->
// FF1+GELU -> FF2+res -> h. Then LN1 (or final LN) -> QKV (TAIL=0) or
// Wout (TAIL=1). All fragment maps / DMA swizzle identical to verified cores.
// ---------------------------------------------------------------------------
template<int DO_FFN, int TAIL>
__global__ __launch_bounds__(256) void mega(
    const ushort* __restrict__ Ob, const ushort* __restrict__ WoT,
    const float* __restrict__ bo, float* __restrict__ h,
    const float* __restrict__ ln2g, const float* __restrict__ ln2b,
    const ushort* __restrict__ W1T, const float* __restrict__ b1,
    const ushort* __restrict__ W2T, const float* __restrict__ b2,
    const float* __restrict__ ln1g, const float* __restrict__ ln1b,
    const ushort* __restrict__ WqT, const ushort* __restrict__ WkT,
    const ushort* __restrict__ WvT,
    const float* __restrict__ bq, const float* __restrict__ bk,
    const float* __restrict__ bv,
    ushort* __restrict__ Qb, ushort* __restrict__ Kb, ushort* __restrict__ Vt,
    float* __restrict__ outm)
{
    __shared__ __align__(16) ushort sW[2 * 16384];   // 64 KB W stream
    __shared__ __align__(16) ushort sA[16 * 264];    // 8.25 KB A-tile
    __shared__ __align__(16) float  sH[16 * 256];    // 16 KB residual rows
    __shared__ __align__(16) ushort sF[16 * 1032];   // 33 KB FF1 out

    const int tid  = threadIdx.x;
    const int lane = tid & 63;
    const int wid  = tid >> 6;
    const int g = lane >> 4, nn = lane & 15;
    const int row0 = blockIdx.x * 16;

    // load h rows -> sH (coalesced)
#pragma unroll
    for (int q = 0; q < 4; ++q) {
        float4 v = *reinterpret_cast<const float4*>(&h[(size_t)row0 * 256 + (q * 256 + tid) * 4]);
        *reinterpret_cast<float4*>(&sH[(q * 256 + tid) * 4]) = v;
    }

    if constexpr (DO_FFN) {
        // attn-out tile -> sA
        {
            const int r = tid >> 4, c = (tid & 15) * 16;
            const ushort* s = Ob + (size_t)(row0 + r) * 256 + c;
            *reinterpret_cast<bf16x8*>(&sA[r * 264 + c])     = *reinterpret_cast<const bf16x8*>(s);
            *reinterpret_cast<bf16x8*>(&sA[r * 264 + c + 8]) = *reinterpret_cast<const bf16x8*>(s + 8);
        }
        // P1: sH += Ob@Wo + bo
        gemm_nchunk(WoT, 256, sA, 264, sW, wid, lane, [&](const f32x4 (&acc)[4]) {
#pragma unroll
            for (int ni = 0; ni < 4; ++ni)
#pragma unroll
            for (int r = 0; r < 4; ++r) {
                const int col = wid * 64 + ni * 16 + nn;
                sH[(g * 4 + r) * 256 + col] += acc[ni][r] + bo[col];
            }
        });
        __syncthreads();                  // sH(post-res) visible to all
        // P2: LN2 -> sA
        ln16(sH, sA, ln2g, ln2b, tid);
        __syncthreads();
        // P3: FF1 (+GELU) -> sF, 4 n-chunks
#pragma unroll
        for (int nc = 0; nc < 4; ++nc) {
            gemm_nchunk(W1T + (size_t)nc * 256 * 256, 256, sA, 264, sW, wid, lane,
                        [&](const f32x4 (&acc)[4]) {
#pragma unroll
                for (int ni = 0; ni < 4; ++ni)
#pragma unroll
                for (int r = 0; r < 4; ++r) {
                    const int col = nc * 256 + wid * 64 + ni * 16 + nn;
                    float v = acc[ni][r] + b1[col];
                    v = 0.5f * v * (1.0f + erff(v * 0.70710678118654752f));
                    sF[(g * 4 + r) * 1032 + col] = (ushort)f2bf(v);
                }
            });
        }
        // P4: sH += sF@W2 + b2
        gemm_nchunk(W2T, 1024, sF, 1032, sW, wid, lane, [&](const f32x4 (&acc)[4]) {
#pragma unroll
            for (int ni = 0; ni < 4; ++ni)
#pragma unroll
            for (int r = 0; r < 4; ++r) {
                const int col = wid * 64 + ni * 16 + nn;
                sH[(g * 4 + r) * 256 + col] += acc[ni][r] + b2[col];
            }
        });
        __syncthreads();
        // write h back (coalesced)
#pragma unroll
        for (int q = 0; q < 4; ++q) {
            float4 v = *reinterpret_cast<const float4*>(&sH[(q * 256 + tid) * 4]);
            *reinterpret_cast<float4*>(&h[(size_t)row0 * 256 + (q * 256 + tid) * 4]) = v;
        }
    }

    __syncthreads();                      // sH ready for LN (entry path too)
    ln16(sH, sA, ln1g, ln1b, tid);        // LN1(next layer) or final LN
    __syncthreads();

    if constexpr (TAIL == 0) {
        // QKV: three n-chunks
        gemm_nchunk(WqT, 256, sA, 264, sW, wid, lane, [&](const f32x4 (&acc)[4]) {
#pragma unroll
            for (int ni = 0; ni < 4; ++ni)
#pragma unroll
            for (int r = 0; r < 4; ++r) {
                const int col = wid * 64 + ni * 16 + nn;
                Qb[(size_t)(row0 + g * 4 + r) * 256 + col] = (ushort)f2bf(acc[ni][r] + bq[col]);
            }
        });
        gemm_nchunk(WkT, 256, sA, 264, sW, wid, lane, [&](const f32x4 (&acc)[4]) {
#pragma unroll
            for (int ni = 0; ni < 4; ++ni)
#pragma unroll
            for (int r = 0; r < 4; ++r) {
                const int col = wid * 64 + ni * 16 + nn;
                Kb[(size_t)(row0 + g * 4 + r) * 256 + col] = (ushort)f2bf(acc[ni][r] + bk[col]);
            }
        });
        gemm_nchunk(WvT, 256, sA, 264, sW, wid, lane, [&](const f32x4 (&acc)[4]) {
#pragma unroll
            for (int ni = 0; ni < 4; ++ni)
#pragma unroll
            for (int r = 0; r < 4; ++r) {
                const int m = row0 + g * 4 + r;
                const int col = wid * 64 + ni * 16 + nn;
                const int b = m >> 11, l = m & 2047;
                const int hh = col >> 5, d = col & 31;
                Vt[(size_t)((b * 8 + hh) * 32 + d) * L_ + l] = (ushort)f2bf(acc[ni][r] + bv[col]);
            }
        });
    } else {
        // Final: out = LN(h)@Wout + bout   (WqT slot carries WoutT, bq carries bout)
        gemm_nchunk(WqT, 256, sA, 264, sW, wid, lane, [&](const f32x4 (&acc)[4]) {
#pragma unroll
            for (int ni = 0; ni < 4; ++ni)
#pragma unroll
            for (int r = 0; r < 4; ++r) {
                const int col = wid * 64 + ni * 16 + nn;
                outm[(size_t)(row0 + g * 4 + r) * 256 + col] = acc[ni][r] + bq[col];
            }
        });
    }
}

// ---------------------------------------------------------------------------
// MFMA evidence attention (verified) + fused uncertainty finalize.
// ---------------------------------------------------------------------------
__global__ __launch_bounds__(256) void attn_mfma(
    const ushort* __restrict__ Qb, const ushort* __restrict__ Kb,
    const ushort* __restrict__ Vt, ushort* __restrict__ O,
    float* __restrict__ unc, const float* __restrict__ ev_scale,
    const float* __restrict__ ev_bias, int layer,
    float* __restrict__ out_unc, float* __restrict__ out_abst)
{
    const int bh = blockIdx.y;
    const int b  = bh >> 3;
    const int h  = bh & 7;
    const int tid  = threadIdx.x;
    const int wv   = tid >> 6;
    const int lane = tid & 63;
    const int g = lane >> 4;
    const int n = lane & 15;
    const int q  = blockIdx.x * 64 + wv * 16 + n;
    const float scale = ev_scale[layer];
    const float cb    = 1.0f + ev_bias[layer];
    const float isq   = 0.17677669529663687f;   // 1/sqrt(32)

    __shared__ __align__(16) ushort sK[2][64][40];
    __shared__ __align__(16) ushort sV[2][32][72];

    const size_t qk0 = (size_t)b * L_ * D_ + h * HD_;

    bf16x8 qf;
    {
        const bf16x8 qr = *reinterpret_cast<const bf16x8*>(&Qb[qk0 + (size_t)q * D_ + g * 8]);
#pragma unroll
        for (int j = 0; j < 8; ++j) {
            const float qv = __builtin_bit_cast(float, ((unsigned)(unsigned short)qr[j]) << 16);
            qf[j] = f2bf(qv * isq);
        }
    }
    bf16x8 ones;
#pragma unroll
    for (int j = 0; j < 8; ++j) ones[j] = (short)0x3F80;

    const int krow = tid >> 2, kch = (tid & 3) * 8;
    const int vrow = tid >> 3, vch = (tid & 7) * 8;
    const ushort* ksrc = Kb + qk0 + (size_t)krow * D_ + kch;
    const ushort* vsrc = Vt + (size_t)((b * 8 + h) * 32 + vrow) * L_ + vch;

    f32x4 acc0 = {0.f, 0.f, 0.f, 0.f};
    f32x4 acc1 = {0.f, 0.f, 0.f, 0.f};
    f32x4 accS = {0.f, 0.f, 0.f, 0.f};
    const f32x4 zero = {0.f, 0.f, 0.f, 0.f};

    bf16x8 kreg = *reinterpret_cast<const bf16x8*>(ksrc);
    bf16x8 vreg = *reinterpret_cast<const bf16x8*>(vsrc);

    int cur = 0;
    for (int t = 0; t < L_; t += 64) {
        *reinterpret_cast<bf16x8*>(&sK[cur][krow][kch]) = kreg;
        *reinterpret_cast<bf16x8*>(&sV[cur][vrow][vch]) = vreg;
        if (t + 64 < L_) {
            kreg = *reinterpret_cast<const bf16x8*>(ksrc + (size_t)(t + 64) * D_);
            vreg = *reinterpret_cast<const bf16x8*>(vsrc + (t + 64));
        }
        __syncthreads();

#pragma unroll
        for (int tt = 0; tt < 64; tt += 32) {
            bf16x8 kf0 = *reinterpret_cast<const bf16x8*>(&sK[cur][tt + n][g * 8]);
            bf16x8 kf1 = *reinterpret_cast<const bf16x8*>(&sK[cur][tt + 16 + n][g * 8]);

            f32x4 s0 = __builtin_amdgcn_mfma_f32_16x16x32_bf16(kf0, qf, zero, 0, 0, 0);
            f32x4 s1 = __builtin_amdgcn_mfma_f32_16x16x32_bf16(kf1, qf, zero, 0, 0, 0);

            short4 va = *reinterpret_cast<const short4*>(&sV[cur][n][tt + g * 4]);
            short4 vb = *reinterpret_cast<const short4*>(&sV[cur][n][tt + 16 + g * 4]);
            short4 vc = *reinterpret_cast<const short4*>(&sV[cur][n + 16][tt + g * 4]);
            short4 vd = *reinterpret_cast<const short4*>(&sV[cur][n + 16][tt + 16 + g * 4]);
            bf16x8 vf0 = {va.x, va.y, va.z, va.w, vb.x, vb.y, vb.z, vb.w};
            bf16x8 vf1 = {vc.x, vc.y, vc.z, vc.w, vd.x, vd.y, vd.z, vd.w};

            bf16x8 pa;
#pragma unroll
            for (int r = 0; r < 4; ++r) pa[r]     = f2bf(fmaf(__expf(s0[r]), scale, cb));
#pragma unroll
            for (int r = 0; r < 4; ++r) pa[r + 4] = f2bf(fmaf(__expf(s1[r]), scale, cb));

            acc0 = __builtin_amdgcn_mfma_f32_16x16x32_bf16(vf0, pa, acc0, 0, 0, 0);
            acc1 = __builtin_amdgcn_mfma_f32_16x16x32_bf16(vf1, pa, acc1, 0, 0, 0);
            accS = __builtin_amdgcn_mfma_f32_16x16x32_bf16(ones, pa, accS, 0, 0, 0);
        }
        cur ^= 1;
    }

    const float inv = 1.0f / accS[0];

    ushort* op = &O[qk0 + (size_t)q * D_ + g * 4];
    short4 o0 = {f2bf(acc0[0] * inv), f2bf(acc0[1] * inv), f2bf(acc0[2] * inv), f2bf(acc0[3] * inv)};
    short4 o1 = {f2bf(acc1[0] * inv), f2bf(acc1[1] * inv), f2bf(acc1[2] * inv), f2bf(acc1[3] * inv)};
    *reinterpret_cast<short4*>(op)      = o0;
    *reinterpret_cast<short4*>(op + 16) = o1;

    if (g == 0) {
        const float u = (float)L_ * inv;
        const int uidx = bh * L_ + q;
        if (layer == 0) {
            unc[uidx] = u;                      // '=' : deterministic across replays
        } else if (layer < LY_ - 1) {
            unc[uidx] += u;
        } else {
            const float avg = (unc[uidx] + u) * 0.25f;
            out_unc[uidx]  = avg;
            out_abst[uidx] = (avg > 0.3f) ? 1.0f : 0.0f;
        }
    }
}

// ---------------------------------------------------------------------------
extern "C" void kernel_launch(void* const* d_in, const int* in_sizes, int n_in,
                              void* d_out, int out_size, void* d_ws, size_t ws_size,
                              hipStream_t stream)
{
    const float* x    = (const float*)d_in[0];
    const float* Win  = (const float*)d_in[1];
    const float* bin_ = (const float*)d_in[2];
    const float* Wq   = (const float*)d_in[3];
    const float* bq   = (const float*)d_in[4];
    const float* Wk   = (const float*)d_in[5];
    const float* bk   = (const float*)d_in[6];
    const float* Wv   = (const float*)d_in[7];
    const float* bv   = (const float*)d_in[8];
    const float* Wo   = (const float*)d_in[9];
    const float* bo   = (const float*)d_in[10];
    const float* evs  = (const float*)d_in[11];
    const float* evb  = (const float*)d_in[12];
    const float* W1   = (const float*)d_in[13];
    const float* b1   = (const float*)d_in[14];
    const float* W2   = (const float*)d_in[15];
    const float* b2   = (const float*)d_in[16];
    const float* n1g  = (const float*)d_in[17];
    const float* n1b  = (const float*)d_in[18];
    const float* n2g  = (const float*)d_in[19];
    const float* n2b  = (const float*)d_in[20];
    const float* fng  = (const float*)d_in[21];
    const float* fnb  = (const float*)d_in[22];
    const float* Wout = (const float*)d_in[23];
    const float* bout = (const float*)d_in[24];

    char* ws = (char*)d_ws;
    float*  h    = (float*) (ws);                  // 4 MB fp32 residual stream
    ushort* Qb   = (ushort*)(ws + (6  << 20));     // 2 MB
    ushort* Kb   = (ushort*)(ws + (8  << 20));     // 2 MB
    ushort* Vt   = (ushort*)(ws + (10 << 20));     // 2 MB (transposed V)
    ushort* Ob   = (ushort*)(ws + (12 << 20));     // 2 MB (attn out)
    float*  unc  = (float*) (ws + (14 << 20));     // 128 KB
    ushort* T    = (ushort*)(ws + (15 << 20));     // 6.55 MB bf16 weights

    ushort* winT  = T;
    ushort* woutT = T + 65536 * 17 + 2097152;

    float* out_main = (float*)d_out;
    float* out_unc  = out_main + M_ * D_;
    float* out_abst = out_unc + B_ * H_ * L_;

    const dim3 blk(256);
    const dim3 gfirst(4, 64);
    const dim3 gattn(L_ / 64, B_ * H_);

    transpose_weights<<<3200, blk, 0, stream>>>(Win, Wq, Wk, Wv, Wo, W1, W2, Wout, T);
    gemm_first<<<gfirst, blk, 0, stream>>>(x, winT, bin_, h);

    // layer-0 entry: LN1 + QKV only
    mega<0, 0><<<256, blk, 0, stream>>>(nullptr, nullptr, nullptr, h,
                                        nullptr, nullptr, nullptr, nullptr,
                                        nullptr, nullptr,
                                        n1g, n1b,
                                        T + 65536 * 1, T + 65536 * 5, T + 65536 * 9,
                                        bq, bk, bv, Qb, Kb, Vt, nullptr);

    for (int i = 0; i < LY_; ++i) {
        ushort* woT = T + 65536 * (13 + i);
        ushort* w1T = T + 65536 * 17 + i * 262144;
        ushort* w2T = T + 65536 * 17 + 1048576 + i * 262144;

        attn_mfma<<<gattn, blk, 0, stream>>>(Qb, Kb, Vt, Ob, unc, evs, evb, i,
                                             out_unc, out_abst);
        if (i < LY_ - 1) {
            const int j = i + 1;
            mega<1, 0><<<256, blk, 0, stream>>>(
                Ob, woT, bo + i * D_, h, n2g + i * D_, n2b + i * D_,
                w1T, b1 + i * F_, w2T, b2 + i * D_,
                n1g + j * D_, n1b + j * D_,
                T + 65536 * (1 + j), T + 65536 * (5 + j), T + 65536 * (9 + j),
                bq + j * D_, bk + j * D_, bv + j * D_,
                Qb, Kb, Vt, nullptr);
        } else {
            mega<1, 1><<<256, blk, 0, stream>>>(
                Ob, woT, bo + i * D_, h, n2g + i * D_, n2b + i * D_,
                w1T, b1 + i * F_, w2T, b2 + i * D_,
                fng, fnb,
                woutT, nullptr, nullptr,
                bout, nullptr, nullptr,
                nullptr, nullptr, nullptr, out_main);
        }
    }
}

// Round 12
// 299.241 us; speedup vs baseline: 1.0817x; 1.0563x over previous
//
#include <hip/hip_runtime.h>
#include <hip/hip_bf16.h>
#include <math.h>

#define B_  2
#define L_  2048
#define D_  256
#define H_  8
#define HD_ 32
#define F_  1024
#define LY_ 4
#define M_  (B_*L_)

typedef __attribute__((ext_vector_type(8))) short bf16x8;   // 8 bf16 in 4 VGPRs
typedef __attribute__((ext_vector_type(4))) float f32x4;

static __device__ __forceinline__ short f2bf(float f) {
    return __builtin_bit_cast(short, __float2bfloat16(f));
}

static __device__ __forceinline__ void gload_lds16(const ushort* g, ushort* l) {
    __builtin_amdgcn_global_load_lds(
        (const __attribute__((address_space(1))) void*)g,
        (__attribute__((address_space(3))) void*)l, 16, 0, 0);
}

// ---------------------------------------------------------------------------
// Weight transpose + fp32->bf16:  W[K][N] -> Wt[N][K] bf16  (round-6 verified)
// ---------------------------------------------------------------------------
__global__ __launch_bounds__(256) void transpose_weights(
    const float* __restrict__ Win, const float* __restrict__ Wq,
    const float* __restrict__ Wk,  const float* __restrict__ Wv,
    const float* __restrict__ Wo,  const float* __restrict__ W1,
    const float* __restrict__ W2,  const float* __restrict__ Wout,
    ushort* __restrict__ T)
{
    const int bid = blockIdx.x;
    const float* src; ushort* dst; int K, N, tt;
    if (bid < 64)        { src = Win; dst = T; K = 256; N = 256; tt = bid; }
    else if (bid < 1088) {
        int i = bid - 64; int which = i >> 8; int l = (i >> 6) & 3; tt = i & 63;
        K = 256; N = 256;
        const float* s4[4] = {Wq, Wk, Wv, Wo};
        src = s4[which] + l * 65536;
        dst = T + 65536 * (1 + which * 4 + l);
    } else if (bid < 2112) {
        int i = bid - 1088; int l = i >> 8; tt = i & 255; K = 256; N = 1024;
        src = W1 + l * 262144; dst = T + 65536 * 17 + l * 262144;
    } else if (bid < 3136) {
        int i = bid - 2112; int l = i >> 8; tt = i & 255; K = 1024; N = 256;
        src = W2 + l * 262144; dst = T + 65536 * 17 + 1048576 + l * 262144;
    } else {
        src = Wout; dst = T + 65536 * 17 + 2097152; K = 256; N = 256; tt = bid - 3136;
    }
    const int ntn = N >> 5;
    const int tk = tt / ntn, tn = tt % ntn;
    __shared__ float ld[32][33];
    const int t = threadIdx.x;
    const int r = t >> 3, c4 = (t & 7) * 4;
    float4 v = *reinterpret_cast<const float4*>(&src[(size_t)(tk * 32 + r) * N + tn * 32 + c4]);
    ld[r][c4 + 0] = v.x; ld[r][c4 + 1] = v.y; ld[r][c4 + 2] = v.z; ld[r][c4 + 3] = v.w;
    __syncthreads();
    short4 o;
    o.x = f2bf(ld[c4 + 0][r]);
    o.y = f2bf(ld[c4 + 1][r]);
    o.z = f2bf(ld[c4 + 2][r]);
    o.w = f2bf(ld[c4 + 3][r]);
    *reinterpret_cast<short4*>(&dst[(size_t)(tn * 32 + r) * K + tk * 32 + c4]) = o;
}

// ---------------------------------------------------------------------------
__global__ __launch_bounds__(256) void f32_to_bf16(
    const float* __restrict__ in, ushort* __restrict__ out)
{
    const int i = (blockIdx.x * 256 + threadIdx.x) * 4;
    float4 v = *reinterpret_cast<const float4*>(&in[i]);
    short4 o = {f2bf(v.x), f2bf(v.y), f2bf(v.z), f2bf(v.w)};
    *reinterpret_cast<short4*>(&out[i]) = o;
}

// ---------------------------------------------------------------------------
// bf16 MFMA GEMM core v2 (round-6 verified): async global_load_lds staging,
// double-buffered, one barrier per BK=64, both-sides XOR swizzle.
// ---------------------------------------------------------------------------
__device__ __forceinline__ void gemm_core64(
    const ushort* __restrict__ A, const ushort* __restrict__ Wt, int K,
    int row0, int col0, ushort* sA, ushort* sW, f32x4 acc[2][2])
{
    const int tid  = threadIdx.x;
    const int lane = tid & 63;
    const int wid  = tid >> 6;
    const int wr = wid >> 1, wc = wid & 1;
    const int g = lane >> 4, nn = lane & 15;

    const int r0 = tid >> 3;
    const int sx = ((tid & 7) ^ (r0 & 7)) << 3;

    const ushort* Ap = &A[(size_t)(row0 + r0) * K + sx];
    const ushort* Wp = &Wt[(size_t)(col0 + r0) * K + sx];
    const size_t rstep = (size_t)32 * K;

    ushort* ldsA = sA + wid * 512;
    ushort* ldsW = sW + wid * 512;

    gload_lds16(Ap,         ldsA);
    gload_lds16(Ap + rstep, ldsA + 2048);
    gload_lds16(Wp,         ldsW);
    gload_lds16(Wp + rstep, ldsW + 2048);

    const int ra = (wr * 32 + nn) * 64, rb = ra + 16 * 64;
    const int rc = (wc * 32 + nn) * 64, rd = rc + 16 * 64;
    const int m7 = nn & 7;

    int cur = 0;
    __syncthreads();
    for (int k0 = 0; k0 < K; k0 += 64) {
        if (k0 + 64 < K) {
            ushort* lA = ldsA + (cur ^ 1) * 4096;
            ushort* lW = ldsW + (cur ^ 1) * 4096;
            gload_lds16(Ap + k0 + 64,         lA);
            gload_lds16(Ap + k0 + 64 + rstep, lA + 2048);
            gload_lds16(Wp + k0 + 64,         lW);
            gload_lds16(Wp + k0 + 64 + rstep, lW + 2048);
        }
        const ushort* a = sA + cur * 4096;
        const ushort* w = sW + cur * 4096;
#pragma unroll
        for (int sk = 0; sk < 2; ++sk) {
            const int sw = ((sk * 4 + g) ^ m7) << 3;
            bf16x8 a0 = *reinterpret_cast<const bf16x8*>(&a[ra + sw]);
            bf16x8 a1 = *reinterpret_cast<const bf16x8*>(&a[rb + sw]);
            bf16x8 w0 = *reinterpret_cast<const bf16x8*>(&w[rc + sw]);
            bf16x8 w1 = *reinterpret_cast<const bf16x8*>(&w[rd + sw]);
            acc[0][0] = __builtin_amdgcn_mfma_f32_16x16x32_bf16(a0, w0, acc[0][0], 0, 0, 0);
            acc[0][1] = __builtin_amdgcn_mfma_f32_16x16x32_bf16(a0, w1, acc[0][1], 0, 0, 0);
            acc[1][0] = __builtin_amdgcn_mfma_f32_16x16x32_bf16(a1, w0, acc[1][0], 0, 0, 0);
            acc[1][1] = __builtin_amdgcn_mfma_f32_16x16x32_bf16(a1, w1, acc[1][1], 0, 0, 0);
        }
        __syncthreads();
        cur ^= 1;
    }
}

// ---------------------------------------------------------------------------
// Generic GEMM + epilogue. EPI: 0 none, 1 exact GELU, 2 +res (fp32).
// ---------------------------------------------------------------------------
template<int EPI, int OUTBF>
__global__ __launch_bounds__(256) void gemm_bf16(
    const ushort* __restrict__ A, const ushort* __restrict__ Wt,
    const float* __restrict__ bias, const float* __restrict__ res,
    void* __restrict__ Cout, int M, int N, int K)
{
    __shared__ __align__(16) ushort sA[2 * 4096];
    __shared__ __align__(16) ushort sW[2 * 4096];
    const int row0 = blockIdx.y * 64, col0 = blockIdx.x * 64;
    f32x4 acc[2][2] = {};
    gemm_core64(A, Wt, K, row0, col0, sA, sW, acc);

    const int lane = threadIdx.x & 63;
    const int wid  = threadIdx.x >> 6;
    const int wr = wid >> 1, wc = wid & 1;
    const int g = lane >> 4, nn = lane & 15;
#pragma unroll
    for (int mi = 0; mi < 2; ++mi)
#pragma unroll
    for (int ni = 0; ni < 2; ++ni)
#pragma unroll
    for (int r = 0; r < 4; ++r) {
        const int m = row0 + wr * 32 + mi * 16 + g * 4 + r;
        const int c = col0 + wc * 32 + ni * 16 + nn;
        float v = acc[mi][ni][r] + bias[c];
        if (EPI == 1) v = 0.5f * v * (1.0f + erff(v * 0.70710678118654752f));
        if (EPI == 2) v += res[(size_t)m * N + c];
        if (OUTBF) ((ushort*)Cout)[(size_t)m * N + c] = (ushort)f2bf(v);
        else       ((float*)Cout)[(size_t)m * N + c] = v;
    }
}

// ---------------------------------------------------------------------------
// Fused QKV GEMM (round-6 verified).
// ---------------------------------------------------------------------------
__global__ __launch_bounds__(256) void gemm_qkv(
    const ushort* __restrict__ A,
    const ushort* __restrict__ WqT, const ushort* __restrict__ WkT,
    const ushort* __restrict__ WvT,
    const float* __restrict__ bq, const float* __restrict__ bk,
    const float* __restrict__ bv,
    ushort* __restrict__ Qb, ushort* __restrict__ Kb, ushort* __restrict__ Vt)
{
    __shared__ __align__(16) ushort sA[2 * 4096];
    __shared__ __align__(16) ushort sW[2 * 4096];
    const int nb = blockIdx.x;
    const int wsel = nb >> 2;
    const int col0 = (nb & 3) * 64;
    const int row0 = blockIdx.y * 64;
    const ushort* Wt = (wsel == 0) ? WqT : (wsel == 1) ? WkT : WvT;
    const float* bias = (wsel == 0) ? bq : (wsel == 1) ? bk : bv;

    f32x4 acc[2][2] = {};
    gemm_core64(A, Wt, 256, row0, col0, sA, sW, acc);

    const int lane = threadIdx.x & 63;
    const int wid  = threadIdx.x >> 6;
    const int wr = wid >> 1, wc = wid & 1;
    const int g = lane >> 4, nn = lane & 15;
    ushort* QK = (wsel == 0) ? Qb : Kb;
#pragma unroll
    for (int mi = 0; mi < 2; ++mi)
#pragma unroll
    for (int ni = 0; ni < 2; ++ni)
#pragma unroll
    for (int r = 0; r < 4; ++r) {
        const int m = row0 + wr * 32 + mi * 16 + g * 4 + r;
        const int c = col0 + wc * 32 + ni * 16 + nn;
        const float v = acc[mi][ni][r] + bias[c];
        if (wsel < 2) {
            QK[(size_t)m * D_ + c] = (ushort)f2bf(v);
        } else {
            const int b = m >> 11, l = m & 2047;
            const int h = c >> 5,  d = c & 31;
            Vt[(size_t)((b * 8 + h) * 32 + d) * L_ + l] = (ushort)f2bf(v);
        }
    }
}

// ---------------------------------------------------------------------------
// LayerNorm over D=256 -> bf16 out. One block per row.  (round-6 verified)
// ---------------------------------------------------------------------------
__global__ __launch_bounds__(256) void ln_kernel(
    const float* __restrict__ x, const float* __restrict__ g,
    const float* __restrict__ b, ushort* __restrict__ y)
{
    const int row = blockIdx.x;
    const int tid = threadIdx.x;
    const float v = x[row * D_ + tid];
    float s = v, s2 = v * v;
#pragma unroll
    for (int off = 32; off > 0; off >>= 1) {
        s  += __shfl_xor(s,  off);
        s2 += __shfl_xor(s2, off);
    }
    __shared__ float ls[4], ls2[4];
    const int wid = tid >> 6;
    if ((tid & 63) == 0) { ls[wid] = s; ls2[wid] = s2; }
    __syncthreads();
    s  = ls[0]  + ls[1]  + ls[2]  + ls[3];
    s2 = ls2[0] + ls2[1] + ls2[2] + ls2[3];
    const float m   = s * (1.0f / D_);
    const float var = s2 * (1.0f / D_) - m * m;
    const float r   = rsqrtf(var + 1e-5f);
    y[row * D_ + tid] = (ushort)f2bf((v - m) * r * g[tid] + b[tid]);
}

// ---------------------------------------------------------------------------
// MFMA evidence attention v7: round-6 body + DEPTH-2 K/V prefetch.
// Parity-static register slots (A = even tiles, B = odd tiles; loop unrolled
// x2 so all reg indices are compile-time). Each pair is consumed two full
// tile-computes after its load issues -> global latency fully hidden.
// Math order / LDS layout bit-identical to round 6. Fused uncertainty
// finalize on the last layer (verified rounds 7/10/11).
// ---------------------------------------------------------------------------
__global__ __launch_bounds__(256) void attn_mfma(
    const ushort* __restrict__ Qb, const ushort* __restrict__ Kb,
    const ushort* __restrict__ Vt, ushort* __restrict__ O,
    float* __restrict__ unc, const float* __restrict__ ev_scale,
    const float* __restrict__ ev_bias, int layer,
    float* __restrict__ out_unc, float* __restrict__ out_abst)
{
    const int bh = blockIdx.y;
    const int b  = bh >> 3;
    const int h  = bh & 7;
    const int tid  = threadIdx.x;
    const int wv   = tid >> 6;
    const int lane = tid & 63;
    const int g = lane >> 4;
    const int n = lane & 15;
    const int q  = blockIdx.x * 64 + wv * 16 + n;
    const float scale = ev_scale[layer];
    const float cb    = 1.0f + ev_bias[layer];
    const float isq   = 0.17677669529663687f;   // 1/sqrt(32)

    __shared__ __align__(16) ushort sK[2][64][40];
    __shared__ __align__(16) ushort sV[2][32][72];

    const size_t qk0 = (size_t)b * L_ * D_ + h * HD_;

    bf16x8 qf;
    {
        const bf16x8 qr = *reinterpret_cast<const bf16x8*>(&Qb[qk0 + (size_t)q * D_ + g * 8]);
#pragma unroll
        for (int j = 0; j < 8; ++j) {
            const float qv = __builtin_bit_cast(float, ((unsigned)(unsigned short)qr[j]) << 16);
            qf[j] = f2bf(qv * isq);
        }
    }
    bf16x8 ones;
#pragma unroll
    for (int j = 0; j < 8; ++j) ones[j] = (short)0x3F80;

    const int krow = tid >> 2, kch = (tid & 3) * 8;
    const int vrow = tid >> 3, vch = (tid & 7) * 8;
    const ushort* ksrc = Kb + qk0 + (size_t)krow * D_ + kch;
    const ushort* vsrc = Vt + (size_t)((b * 8 + h) * 32 + vrow) * L_ + vch;

    f32x4 acc0 = {0.f, 0.f, 0.f, 0.f};
    f32x4 acc1 = {0.f, 0.f, 0.f, 0.f};
    f32x4 accS = {0.f, 0.f, 0.f, 0.f};
    const f32x4 zero = {0.f, 0.f, 0.f, 0.f};

    // depth-2 prologue: tiles 0 (slot A) and 64 (slot B)
    bf16x8 kA = *reinterpret_cast<const bf16x8*>(ksrc);
    bf16x8 vA = *reinterpret_cast<const bf16x8*>(vsrc);
    bf16x8 kB = *reinterpret_cast<const bf16x8*>(ksrc + (size_t)64 * D_);
    bf16x8 vB = *reinterpret_cast<const bf16x8*>(vsrc + 64);

#define ATTN_TILE(BUF)                                                          \
    do {                                                                        \
        _Pragma("unroll")                                                       \
        for (int tt = 0; tt < 64; tt += 32) {                                   \
            bf16x8 kf0 = *reinterpret_cast<const bf16x8*>(&sK[BUF][tt + n][g * 8]);      \
            bf16x8 kf1 = *reinterpret_cast<const bf16x8*>(&sK[BUF][tt + 16 + n][g * 8]); \
            f32x4 s0 = __builtin_amdgcn_mfma_f32_16x16x32_bf16(kf0, qf, zero, 0, 0, 0);  \
            f32x4 s1 = __builtin_amdgcn_mfma_f32_16x16x32_bf16(kf1, qf, zero, 0, 0, 0);  \
            short4 va = *reinterpret_cast<const short4*>(&sV[BUF][n][tt + g * 4]);       \
            short4 vb = *reinterpret_cast<const short4*>(&sV[BUF][n][tt + 16 + g * 4]);  \
            short4 vc = *reinterpret_cast<const short4*>(&sV[BUF][n + 16][tt + g * 4]);  \
            short4 vd = *reinterpret_cast<const short4*>(&sV[BUF][n + 16][tt + 16 + g * 4]); \
            bf16x8 vf0 = {va.x, va.y, va.z, va.w, vb.x, vb.y, vb.z, vb.w};      \
            bf16x8 vf1 = {vc.x, vc.y, vc.z, vc.w, vd.x, vd.y, vd.z, vd.w};      \
            bf16x8 pa;                                                          \
            _Pragma("unroll")                                                   \
            for (int r = 0; r < 4; ++r) pa[r]     = f2bf(fmaf(__expf(s0[r]), scale, cb)); \
            _Pragma("unroll")                                                   \
            for (int r = 0; r < 4; ++r) pa[r + 4] = f2bf(fmaf(__expf(s1[r]), scale, cb)); \
            acc0 = __builtin_amdgcn_mfma_f32_16x16x32_bf16(vf0, pa, acc0, 0, 0, 0); \
            acc1 = __builtin_amdgcn_mfma_f32_16x16x32_bf16(vf1, pa, acc1, 0, 0, 0); \
            accS = __builtin_amdgcn_mfma_f32_16x16x32_bf16(ones, pa, accS, 0, 0, 0); \
        }                                                                       \
    } while (0)

    for (int t = 0; t < L_; t += 128) {
        // even tile t: slot A -> LDS[0]
        *reinterpret_cast<bf16x8*>(&sK[0][krow][kch]) = kA;
        *reinterpret_cast<bf16x8*>(&sV[0][vrow][vch]) = vA;
        if (t + 128 < L_) {
            kA = *reinterpret_cast<const bf16x8*>(ksrc + (size_t)(t + 128) * D_);
            vA = *reinterpret_cast<const bf16x8*>(vsrc + (t + 128));
        }
        __syncthreads();
        ATTN_TILE(0);

        // odd tile t+64: slot B -> LDS[1]
        *reinterpret_cast<bf16x8*>(&sK[1][krow][kch]) = kB;
        *reinterpret_cast<bf16x8*>(&sV[1][vrow][vch]) = vB;
        if (t + 192 < L_) {
            kB = *reinterpret_cast<const bf16x8*>(ksrc + (size_t)(t + 192) * D_);
            vB = *reinterpret_cast<const bf16x8*>(vsrc + (t + 192));
        }
        __syncthreads();
        ATTN_TILE(1);
    }
#undef ATTN_TILE

    const float inv = 1.0f / accS[0];

    ushort* op = &O[qk0 + (size_t)q * D_ + g * 4];
    short4 o0 = {f2bf(acc0[0] * inv), f2bf(acc0[1] * inv), f2bf(acc0[2] * inv), f2bf(acc0[3] * inv)};
    short4 o1 = {f2bf(acc1[0] * inv), f2bf(acc1[1] * inv), f2bf(acc1[2] * inv), f2bf(acc1[3] * inv)};
    *reinterpret_cast<short4*>(op)      = o0;
    *reinterpret_cast<short4*>(op + 16) = o1;

    if (g == 0) {
        const float u = (float)L_ * inv;
        const int uidx = bh * L_ + q;
        if (layer == 0) {
            unc[uidx] = u;                      // '=' : deterministic across replays
        } else if (layer < LY_ - 1) {
            unc[uidx] += u;
        } else {
            const float avg = (unc[uidx] + u) * 0.25f;
            out_unc[uidx]  = avg;
            out_abst[uidx] = (avg > 0.3f) ? 1.0f : 0.0f;
        }
    }
}

// ---------------------------------------------------------------------------
extern "C" void kernel_launch(void* const* d_in, const int* in_sizes, int n_in,
                              void* d_out, int out_size, void* d_ws, size_t ws_size,
                              hipStream_t stream)
{
    const float* x    = (const float*)d_in[0];
    const float* Win  = (const float*)d_in[1];
    const float* bin_ = (const float*)d_in[2];
    const float* Wq   = (const float*)d_in[3];
    const float* bq   = (const float*)d_in[4];
    const float* Wk   = (const float*)d_in[5];
    const float* bk   = (const float*)d_in[6];
    const float* Wv   = (const float*)d_in[7];
    const float* bv   = (const float*)d_in[8];
    const float* Wo   = (const float*)d_in[9];
    const float* bo   = (const float*)d_in[10];
    const float* evs  = (const float*)d_in[11];
    const float* evb  = (const float*)d_in[12];
    const float* W1   = (const float*)d_in[13];
    const float* b1   = (const float*)d_in[14];
    const float* W2   = (const float*)d_in[15];
    const float* b2   = (const float*)d_in[16];
    const float* n1g  = (const float*)d_in[17];
    const float* n1b  = (const float*)d_in[18];
    const float* n2g  = (const float*)d_in[19];
    const float* n2b  = (const float*)d_in[20];
    const float* fng  = (const float*)d_in[21];
    const float* fnb  = (const float*)d_in[22];
    const float* Wout = (const float*)d_in[23];
    const float* bout = (const float*)d_in[24];

    char* ws = (char*)d_ws;
    float*  h    = (float*) (ws);                  // 4 MB fp32 residual stream
    ushort* tmpb = (ushort*)(ws + (4  << 20));     // 2 MB bf16 (LN out / x-bf16)
    ushort* Qb   = (ushort*)(ws + (6  << 20));     // 2 MB
    ushort* Kb   = (ushort*)(ws + (8  << 20));     // 2 MB
    ushort* Vt   = (ushort*)(ws + (10 << 20));     // 2 MB (transposed V)
    ushort* Ob   = (ushort*)(ws + (12 << 20));     // 2 MB (attn out)
    ushort* ffb  = (ushort*)(ws + (6  << 20));     // 8 MB, overlays Qb..Ob (dead by FF1)
    float*  unc  = (float*) (ws + (14 << 20));     // 128 KB
    ushort* T    = (ushort*)(ws + (15 << 20));     // 6.55 MB transposed bf16 weights

    ushort* winT  = T;
    ushort* woutT = T + 65536 * 17 + 2097152;

    float* out_main = (float*)d_out;
    float* out_unc  = out_main + M_ * D_;
    float* out_abst = out_unc + B_ * H_ * L_;

    const dim3 blk(256);
    const dim3 g256(4, 64);     // N=256 GEMMs
    const dim3 g1024(16, 64);   // N=1024 GEMM
    const dim3 gqkv(12, 64);
    const dim3 gattn(L_ / 64, B_ * H_);

    transpose_weights<<<3200, blk, 0, stream>>>(Win, Wq, Wk, Wv, Wo, W1, W2, Wout, T);
    f32_to_bf16<<<1024, blk, 0, stream>>>(x, tmpb);
    gemm_bf16<0, 0><<<g256, blk, 0, stream>>>(tmpb, winT, bin_, nullptr, h, M_, D_, D_);

    for (int i = 0; i < LY_; ++i) {
        ushort* wqT = T + 65536 * (1 + i);
        ushort* wkT = T + 65536 * (5 + i);
        ushort* wvT = T + 65536 * (9 + i);
        ushort* woT = T + 65536 * (13 + i);
        ushort* w1T = T + 65536 * 17 + i * 262144;
        ushort* w2T = T + 65536 * 17 + 1048576 + i * 262144;

        ln_kernel<<<M_, blk, 0, stream>>>(h, n1g + i * D_, n1b + i * D_, tmpb);
        gemm_qkv<<<gqkv, blk, 0, stream>>>(tmpb, wqT, wkT, wvT,
                                           bq + i * D_, bk + i * D_, bv + i * D_,
                                           Qb, Kb, Vt);
        attn_mfma<<<gattn, blk, 0, stream>>>(Qb, Kb, Vt, Ob, unc, evs, evb, i,
                                             out_unc, out_abst);
        gemm_bf16<2, 0><<<g256, blk, 0, stream>>>(Ob, woT, bo + i * D_, h, h, M_, D_, D_);
        ln_kernel<<<M_, blk, 0, stream>>>(h, n2g + i * D_, n2b + i * D_, tmpb);
        gemm_bf16<1, 1><<<g1024, blk, 0, stream>>>(tmpb, w1T, b1 + i * F_, nullptr, ffb, M_, F_, D_);
        gemm_bf16<2, 0><<<g256, blk, 0, stream>>>(ffb, w2T, b2 + i * D_, h, h, M_, D_, F_);
    }

    ln_kernel<<<M_, blk, 0, stream>>>(h, fng, fnb, tmpb);
    gemm_bf16<0, 0><<<g256, blk, 0, stream>>>(tmpb, woutT, bout, nullptr, out_main, M_, D_, D_);
}